// Round 2
// baseline (126308.875 us; speedup 1.0000x reference)
//
#include <hip/hip_runtime.h>
#include <cstdint>
#include <cstddef>

// ============================================================================
// 2-layer GRU (B=512,S=512,C=32,H=512) + projection (3072x512), MI355X gfx950.
// Persistent kernel, 256 blocks x 256 threads, 2 grid barriers / step.
// All recurrence GEMMs use 3-term split-f16 MFMA (hi + scaled-lo operands,
// separate correction accumulator) => effectively f32-accurate matmuls.
// State carried f32; H1 double-buffered by parity (fixes phase-B race).
// ============================================================================

typedef _Float16 f16;
typedef _Float16 half8 __attribute__((ext_vector_type(8)));
typedef float f32x4 __attribute__((ext_vector_type(4)));

#define NT 256
#define NBLK 256
#define SEQ 512
#define SC 2048.0f
#define INV_SC (1.0f / 2048.0f)

// ---- workspace layout (bytes) ----
constexpr size_t SZ_W512 = (size_t)1536 * 512 * 2;
constexpr size_t OFF_WH0H = 0;
constexpr size_t OFF_WH0L = OFF_WH0H + SZ_W512;
constexpr size_t OFF_WI1H = OFF_WH0L + SZ_W512;
constexpr size_t OFF_WI1L = OFF_WI1H + SZ_W512;
constexpr size_t OFF_WH1H = OFF_WI1L + SZ_W512;
constexpr size_t OFF_WH1L = OFF_WH1H + SZ_W512;
constexpr size_t OFF_WPH  = OFF_WH1L + SZ_W512;            // 3072x512 f16 (hi only)
constexpr size_t OFF_WI0H = OFF_WPH  + (size_t)3072*512*2; // 1536x32 f16
constexpr size_t OFF_WI0L = OFF_WI0H + (size_t)1536*32*2;
constexpr size_t OFF_H0   = OFF_WI0L + (size_t)1536*32*2;  // 512x512 f32
constexpr size_t OFF_H1A  = OFF_H0   + (size_t)512*512*4;  // f32 buf A
constexpr size_t OFF_H1B  = OFF_H1A  + (size_t)512*512*4;  // f32 buf B
constexpr size_t OFF_H0HI = OFF_H1B  + (size_t)512*512*4;  // f16
constexpr size_t OFF_H0LO = OFF_H0HI + (size_t)512*512*2;
constexpr size_t OFF_H1HIA= OFF_H0LO + (size_t)512*512*2;
constexpr size_t OFF_H1LOA= OFF_H1HIA+ (size_t)512*512*2;
constexpr size_t OFF_H1HIB= OFF_H1LOA+ (size_t)512*512*2;
constexpr size_t OFF_H1LOB= OFF_H1HIB+ (size_t)512*512*2;
constexpr size_t OFF_RH0H = OFF_H1LOB+ (size_t)512*512*2;  // r0*h0 hi
constexpr size_t OFF_RH0L = OFF_RH0H + (size_t)512*512*2;  // r0*h0 lo_s
constexpr size_t OFF_Z0   = OFF_RH0L + (size_t)512*512*2;  // 512x512 f32
constexpr size_t OFF_GI1  = OFF_Z0   + (size_t)512*512*4;  // 512x1536 f32
constexpr size_t OFF_RZ1  = OFF_GI1  + (size_t)512*1536*4; // 512x1024 f32
constexpr size_t OFF_BAR  = OFF_RZ1  + (size_t)512*1024*4; // 512 uints
constexpr size_t WS_NEED  = OFF_BAR + 2048;                // ~26.7 MB

__device__ __forceinline__ float sigm(float v) { return 1.f / (1.f + __expf(-v)); }
__device__ __forceinline__ float tanh_f(float v) { float e = __expf(2.f * v); return 1.f - 2.f / (e + 1.f); }
__device__ __forceinline__ void split2(float v, f16& hi, f16& lo) {
  f16 h = (f16)v; hi = h; lo = (f16)((v - (float)h) * SC);
}

// swizzled 16B LDS store: logical [row][128B], byte ^= (row&7)<<4
__device__ __forceinline__ void ds_put16(char* dst, int row, int colHalf, uint4 v) {
  *(uint4*)(dst + ((row * 128 + colHalf * 2) ^ ((row & 7) << 4))) = v;
}

// ---- single-precision staging (projection only) ----
template<int NG, int TOTAL>
__device__ __forceinline__ void load_ldm(const f16* g, int r0, int k0, uint4 (&v)[NG]) {
#pragma unroll
  for (int j = 0; j < NG; ++j) {
    int idx = threadIdx.x + j * NT;
    if ((TOTAL & 255) == 0 || idx < TOTAL)
      v[j] = *(const uint4*)(g + (size_t)(r0 + (idx >> 3)) * 512 + k0 + (idx & 7) * 8);
  }
}
template<int NG, int TOTAL>
__device__ __forceinline__ void write_ch(char* dst, uint4 (&v)[NG]) {
#pragma unroll
  for (int j = 0; j < NG; ++j) {
    int idx = threadIdx.x + j * NT;
    if ((TOTAL & 255) == 0 || idx < TOTAL)
      ds_put16(dst, idx >> 3, (idx & 7) * 8, v[j]);
  }
}

// ---- paired (hi/lo) staging: sources ld=512, granule = 8 halves ----
template<int NG>
__device__ __forceinline__ void load_pair(const f16* hi, const f16* lo, int r0, int k0,
                                          uint4 (&hv)[NG], uint4 (&lv)[NG]) {
#pragma unroll
  for (int j = 0; j < NG; ++j) {
    int idx = threadIdx.x + j * NT;
    size_t off = (size_t)(r0 + (idx >> 3)) * 512 + k0 + (idx & 7) * 8;
    hv[j] = *(const uint4*)(hi + off);
    lv[j] = *(const uint4*)(lo + off);
  }
}
template<int NG, int RLO>
__device__ __forceinline__ void write_pair(char* dst, uint4 (&hv)[NG], uint4 (&lv)[NG]) {
#pragma unroll
  for (int j = 0; j < NG; ++j) {
    int idx = threadIdx.x + j * NT;
    int r = idx >> 3, c = (idx & 7) * 8;
    ds_put16(dst, r, c, hv[j]);
    ds_put16(dst, r + RLO, c, lv[j]);
  }
}

// stage x (f32 (B,S,C)) -> f16 hi rows r, scaled-lo rows r+128 (32 halves/row)
template<int ROWS>
__device__ __forceinline__ void stage_x(const float* x, int m0, int step, char* As) {
  for (int idx = threadIdx.x; idx < ROWS * 4; idx += NT) {
    int r = idx >> 2, g8 = idx & 3;
    const float* src = x + (((size_t)(m0 + r)) << 14) + (step << 5) + g8 * 8;
    float4 f0 = ((const float4*)src)[0];
    float4 f1 = ((const float4*)src)[1];
    float v[8] = {f0.x, f0.y, f0.z, f0.w, f1.x, f1.y, f1.z, f1.w};
    union { uint4 u; f16 e[8]; } H, L;
#pragma unroll
    for (int e = 0; e < 8; ++e) split2(v[e], H.e[e], L.e[e]);
    ds_put16(As, r, g8 * 8, H.u);
    ds_put16(As, r + 128, g8 * 8, L.u);
  }
}

// on-the-fly A-operand for n1 GEMM from f32 sources: rh1 = sigm(gi_r+rz_r)*h1
__device__ __forceinline__ void load_rh1(const float* GI1, const float* RZ1, const float* H1,
                                         int m0, int ch, float4 (&gv)[4], float4 (&rv)[4], float4 (&hv)[4]) {
#pragma unroll
  for (int j = 0; j < 2; ++j) {
    int idx = threadIdx.x + j * NT;
    int r = idx >> 3, k = ch * 64 + (idx & 7) * 8;
    const float* g = GI1 + (size_t)(m0 + r) * 1536 + k;
    const float* z = RZ1 + (size_t)(m0 + r) * 1024 + k;
    const float* h = H1  + (size_t)(m0 + r) * 512 + k;
    gv[2*j] = ((const float4*)g)[0]; gv[2*j+1] = ((const float4*)g)[1];
    rv[2*j] = ((const float4*)z)[0]; rv[2*j+1] = ((const float4*)z)[1];
    hv[2*j] = ((const float4*)h)[0]; hv[2*j+1] = ((const float4*)h)[1];
  }
}
__device__ __forceinline__ void write_rh1(char* As, float4 (&gv)[4], float4 (&rv)[4], float4 (&hv)[4]) {
#pragma unroll
  for (int j = 0; j < 2; ++j) {
    int idx = threadIdx.x + j * NT;
    int r = idx >> 3, g8 = idx & 7;
    const float* gg = (const float*)&gv[2*j];
    const float* rr = (const float*)&rv[2*j];
    const float* hh = (const float*)&hv[2*j];
    union { uint4 u; f16 e[8]; } H, L;
#pragma unroll
    for (int e = 0; e < 8; ++e) {
      float s = sigm(gg[e] + rr[e]);
      split2(s * hh[e], H.e[e], L.e[e]);
    }
    ds_put16(As, r, g8 * 8, H.u);
    ds_put16(As, r + 128, g8 * 8, L.u);
  }
}

// ---- MFMA sweeps ----
// A frag: row=lane&15, k=(lane>>4)*8+j ; B frag: col=lane&15, same k.
// C/D: col=lane&15, row=(lane>>4)*4+reg. Lo tiles at +128 rows (A) / +64 (B).
template<int FM, int FN, int KI>
__device__ __forceinline__ void mfma_tile(const char* Asl, const char* Bsl,
                                          int aRow0, int bCol0, f32x4 (&acc)[FM][FN]) {
  const int lane = threadIdx.x & 63;
  const int lr16 = lane & 15;
  const int lkb = (lane >> 4) << 4;
#pragma unroll
  for (int ki = 0; ki < KI; ++ki) {
    half8 a[FM], b[FN];
#pragma unroll
    for (int fm = 0; fm < FM; ++fm) {
      int row = aRow0 + fm * 16 + lr16;
      a[fm] = *(const half8*)(Asl + ((row * 128 + ki * 64 + lkb) ^ ((row & 7) << 4)));
    }
#pragma unroll
    for (int fn = 0; fn < FN; ++fn) {
      int col = bCol0 + fn * 16 + lr16;
      b[fn] = *(const half8*)(Bsl + ((col * 128 + ki * 64 + lkb) ^ ((col & 7) << 4)));
    }
#pragma unroll
    for (int fm = 0; fm < FM; ++fm)
#pragma unroll
      for (int fn = 0; fn < FN; ++fn)
        acc[fm][fn] = __builtin_amdgcn_mfma_f32_16x16x32_f16(a[fm], b[fn], acc[fm][fn], 0, 0, 0);
  }
}

template<int FM, int FN, int KI>
__device__ __forceinline__ void mfma3(const char* Asl, const char* Bsl,
                                      int aRow0, int bCol0,
                                      f32x4 (&am)[FM][FN], f32x4 (&ac)[FM][FN]) {
  const int lane = threadIdx.x & 63;
  const int lr16 = lane & 15;
  const int lkb = (lane >> 4) << 4;
#pragma unroll
  for (int ki = 0; ki < KI; ++ki) {
    half8 ah[FM], al[FM], bh[FN], bl[FN];
#pragma unroll
    for (int fm = 0; fm < FM; ++fm) {
      int row = aRow0 + fm * 16 + lr16;
      int off = (row * 128 + ki * 64 + lkb) ^ ((row & 7) << 4);
      ah[fm] = *(const half8*)(Asl + off);
      al[fm] = *(const half8*)(Asl + off + 16384);   // +128 rows
    }
#pragma unroll
    for (int fn = 0; fn < FN; ++fn) {
      int col = bCol0 + fn * 16 + lr16;
      int off = (col * 128 + ki * 64 + lkb) ^ ((col & 7) << 4);
      bh[fn] = *(const half8*)(Bsl + off);
      bl[fn] = *(const half8*)(Bsl + off + 8192);    // +64 rows
    }
#pragma unroll
    for (int fm = 0; fm < FM; ++fm)
#pragma unroll
      for (int fn = 0; fn < FN; ++fn) {
        am[fm][fn] = __builtin_amdgcn_mfma_f32_16x16x32_f16(ah[fm], bh[fn], am[fm][fn], 0, 0, 0);
        ac[fm][fn] = __builtin_amdgcn_mfma_f32_16x16x32_f16(al[fm], bh[fn], ac[fm][fn], 0, 0, 0);
        ac[fm][fn] = __builtin_amdgcn_mfma_f32_16x16x32_f16(ah[fm], bl[fn], ac[fm][fn], 0, 0, 0);
      }
  }
}

// K=32 fold with packed Wi0 in WX (2 cols per 128B row; hiBase/loBase in rows)
template<int FM, int FN>
__device__ __forceinline__ void mfma_fold(const char* Asl, const char* WXl,
                                          int aRow0, int bCol0, int hiBase, int loBase,
                                          f32x4 (&am)[FM][FN], f32x4 (&ac)[FM][FN]) {
  const int lane = threadIdx.x & 63;
  const int lr16 = lane & 15;
  const int lkb = (lane >> 4) << 4;
  half8 ah[FM], al[FM], bh[FN], bl[FN];
#pragma unroll
  for (int fm = 0; fm < FM; ++fm) {
    int row = aRow0 + fm * 16 + lr16;
    int off = (row * 128 + lkb) ^ ((row & 7) << 4);
    ah[fm] = *(const half8*)(Asl + off);
    al[fm] = *(const half8*)(Asl + off + 16384);
  }
#pragma unroll
  for (int fn = 0; fn < FN; ++fn) {
    int c = bCol0 + fn * 16 + lr16;
    int rh = hiBase + (c >> 1), rl = loBase + (c >> 1);
    int cb = (c & 1) * 64 + lkb;
    bh[fn] = *(const half8*)(WXl + ((rh * 128 + cb) ^ ((rh & 7) << 4)));
    bl[fn] = *(const half8*)(WXl + ((rl * 128 + cb) ^ ((rl & 7) << 4)));
  }
#pragma unroll
  for (int fm = 0; fm < FM; ++fm)
#pragma unroll
    for (int fn = 0; fn < FN; ++fn) {
      am[fm][fn] = __builtin_amdgcn_mfma_f32_16x16x32_f16(ah[fm], bh[fn], am[fm][fn], 0, 0, 0);
      ac[fm][fn] = __builtin_amdgcn_mfma_f32_16x16x32_f16(al[fm], bh[fn], ac[fm][fn], 0, 0, 0);
      ac[fm][fn] = __builtin_amdgcn_mfma_f32_16x16x32_f16(ah[fm], bl[fn], ac[fm][fn], 0, 0, 0);
    }
}

// two-level monotonic grid barrier (no resets => no ABA)
__device__ __forceinline__ void gbar(unsigned* bar, int bid, unsigned lg) {
  __syncthreads();
  if (threadIdx.x == 0) {
    __threadfence();
    unsigned v = __hip_atomic_fetch_add(bar + ((bid >> 5) << 5), 1u,
                                        __ATOMIC_ACQ_REL, __HIP_MEMORY_SCOPE_AGENT);
    if (v == lg * 32u - 1u) {
      unsigned r = __hip_atomic_fetch_add(bar + 256, 1u,
                                          __ATOMIC_ACQ_REL, __HIP_MEMORY_SCOPE_AGENT);
      if (r == lg * 8u - 1u)
        __hip_atomic_store(bar + 288, lg, __ATOMIC_RELEASE, __HIP_MEMORY_SCOPE_AGENT);
    }
    while (__hip_atomic_load(bar + 288, __ATOMIC_ACQUIRE, __HIP_MEMORY_SCOPE_AGENT) < lg)
      __builtin_amdgcn_s_sleep(2);
    __threadfence();
  }
  __syncthreads();
}

// ---------------------------------------------------------------------------
__global__ void gru_setup(const float* __restrict__ Wi0, const float* __restrict__ Wh0,
                          const float* __restrict__ Wi1, const float* __restrict__ Wh1,
                          const float* __restrict__ Wp, char* __restrict__ ws) {
  size_t t = (size_t)blockIdx.x * blockDim.x + threadIdx.x;
  size_t st = (size_t)gridDim.x * blockDim.x;
  f16* wh0h = (f16*)(ws + OFF_WH0H); f16* wh0l = (f16*)(ws + OFF_WH0L);
  f16* wi1h = (f16*)(ws + OFF_WI1H); f16* wi1l = (f16*)(ws + OFF_WI1L);
  f16* wh1h = (f16*)(ws + OFF_WH1H); f16* wh1l = (f16*)(ws + OFF_WH1L);
  f16* wph  = (f16*)(ws + OFF_WPH);
  f16* wi0h = (f16*)(ws + OFF_WI0H); f16* wi0l = (f16*)(ws + OFF_WI0L);
  for (size_t j = t; j < (size_t)1536*512; j += st) {
    split2(Wh0[j], wh0h[j], wh0l[j]);
    split2(Wi1[j], wi1h[j], wi1l[j]);
    split2(Wh1[j], wh1h[j], wh1l[j]);
  }
  for (size_t j = t; j < (size_t)3072*512; j += st) wph[j] = (f16)Wp[j];
  for (size_t j = t; j < (size_t)1536*32; j += st) split2(Wi0[j], wi0h[j], wi0l[j]);
  float* h0 = (float*)(ws + OFF_H0);
  float* h1a = (float*)(ws + OFF_H1A); float* h1b = (float*)(ws + OFF_H1B);
  f16* p0 = (f16*)(ws + OFF_H0HI);  // contiguous f16 zero region: H0HI..RH0L (8 x 0.5MB)
  for (size_t j = t; j < (size_t)512*512; j += st) { h0[j] = 0.f; h1a[j] = 0.f; h1b[j] = 0.f; }
  for (size_t j = t; j < (size_t)512*512*8; j += st) p0[j] = (f16)0.f;
  unsigned* bar = (unsigned*)(ws + OFF_BAR);
  for (size_t j = t; j < 512; j += st) bar[j] = 0u;
}

// ---------------------------------------------------------------------------
__global__ __launch_bounds__(NT, 1) void gru_main(
    const float* __restrict__ x, const float* __restrict__ b0, const float* __restrict__ b1,
    const float* __restrict__ bp, float* __restrict__ out, char* __restrict__ ws)
{
  __shared__ char As[32768];   // 256 rows x 128B: hi rows 0-127, lo rows 128-255
  __shared__ char Bs[16384];   // 128 rows x 128B: hi rows 0-63,  lo rows 64-127
  __shared__ char WX[12288];   // packed Wi0: rz hi r0-31, rz lo r32-63, n hi r64-79, n lo r80-95

  const f16* WH0Hp = (const f16*)(ws + OFF_WH0H); const f16* WH0Lp = (const f16*)(ws + OFF_WH0L);
  const f16* WI1Hp = (const f16*)(ws + OFF_WI1H); const f16* WI1Lp = (const f16*)(ws + OFF_WI1L);
  const f16* WH1Hp = (const f16*)(ws + OFF_WH1H); const f16* WH1Lp = (const f16*)(ws + OFF_WH1L);
  const f16* WPHp  = (const f16*)(ws + OFF_WPH);
  const f16* WI0Hp = (const f16*)(ws + OFF_WI0H); const f16* WI0Lp = (const f16*)(ws + OFF_WI0L);
  float* H0 = (float*)(ws + OFF_H0);
  f16* H0HI = (f16*)(ws + OFF_H0HI); f16* H0LO = (f16*)(ws + OFF_H0LO);
  f16* RH0H = (f16*)(ws + OFF_RH0H); f16* RH0L = (f16*)(ws + OFF_RH0L);
  float* Z0 = (float*)(ws + OFF_Z0);
  float* GI1 = (float*)(ws + OFF_GI1);
  float* RZ1 = (float*)(ws + OFF_RZ1);
  unsigned* bar = (unsigned*)(ws + OFF_BAR);

  const int bid = blockIdx.x;
  const int tid = threadIdx.x;
  const int wid = tid >> 6;
  const int lane = tid & 63;
  const int lr = lane & 15, lh = lane >> 4;

  // phase-A role: 4 M-groups x 56 col-slots of 64
  const bool hasA = bid < 224;
  const int mgA = bid / 56, slotA = bid % 56;
  const int m0A = mgA * 128, col0A = slotA * 64;
  const int typeA = col0A < 1024 ? 0 : (col0A < 2560 ? 1 : 2);  // rz0 / gi1 / rz1
  const int wrow0A = (typeA == 0) ? col0A : (typeA == 1 ? col0A - 1024 : col0A - 2560);
  const int wmA = (wid >> 1) * 64, wnA = (wid & 1) * 32;

  // phase-B role: 8 M-groups x 32 slots of 32
  const int mgB = bid >> 5, slotB = bid & 31;
  const int m0B = mgB * 64;
  const bool isN0 = slotB < 16;
  const int col0B = (isN0 ? slotB : slotB - 16) * 32;
  const int wmB = (wid >> 1) * 32, wnB = (wid & 1) * 16;

  // preload packed Wi0 slices
  if (hasA && typeA == 0) {
    for (int idx = tid; idx < 256; idx += NT) {
      int c = idx >> 2, g = idx & 3;
      uint4 vh = *(const uint4*)(WI0Hp + (size_t)(col0A + c) * 32 + g * 8);
      uint4 vl = *(const uint4*)(WI0Lp + (size_t)(col0A + c) * 32 + g * 8);
      ds_put16(WX, (c >> 1), (c & 1) * 32 + g * 8, vh);
      ds_put16(WX, 32 + (c >> 1), (c & 1) * 32 + g * 8, vl);
    }
  }
  if (isN0) {
    for (int idx = tid; idx < 128; idx += NT) {
      int c = idx >> 2, g = idx & 3;
      uint4 vh = *(const uint4*)(WI0Hp + (size_t)(1024 + col0B + c) * 32 + g * 8);
      uint4 vl = *(const uint4*)(WI0Lp + (size_t)(1024 + col0B + c) * 32 + g * 8);
      ds_put16(WX, 64 + (c >> 1), (c & 1) * 32 + g * 8, vh);
      ds_put16(WX, 80 + (c >> 1), (c & 1) * 32 + g * 8, vl);
    }
  }
  __syncthreads();

  unsigned lg = 0;
  for (int i = 0; i <= SEQ; ++i) {
    const int pw = i & 1;  // H1 write parity; read = opposite
    const float* H1R = (const float*)(ws + (pw ? OFF_H1A : OFF_H1B));
    float*       H1W = (float*)(ws + (pw ? OFF_H1B : OFF_H1A));
    const f16* H1HIr = (const f16*)(ws + (pw ? OFF_H1HIA : OFF_H1HIB));
    const f16* H1LOr = (const f16*)(ws + (pw ? OFF_H1LOA : OFF_H1LOB));
    f16* H1HIw = (f16*)(ws + (pw ? OFF_H1HIB : OFF_H1HIA));
    f16* H1LOw = (f16*)(ws + (pw ? OFF_H1LOB : OFF_H1LOA));

    // ========================= PHASE A =========================
    bool activeA = hasA && (typeA == 0 ? (i < SEQ) : (i >= 1));
    if (activeA) {
      const f16* AsrcH = (typeA == 2) ? H1HIr : H0HI;
      const f16* AsrcL = (typeA == 2) ? H1LOr : H0LO;
      const f16* WsrcH = (typeA == 0) ? WH0Hp : (typeA == 1 ? WI1Hp : WH1Hp);
      const f16* WsrcL = (typeA == 0) ? WH0Lp : (typeA == 1 ? WI1Lp : WH1Lp);
      f32x4 am[4][2] = {}, ac[4][2] = {};
      {
        uint4 avh[4], avl[4], bvh[2], bvl[2];
        load_pair<4>(AsrcH, AsrcL, m0A, 0, avh, avl);
        load_pair<2>(WsrcH, WsrcL, wrow0A, 0, bvh, bvl);
        write_pair<4,128>(As, avh, avl);
        write_pair<2,64>(Bs, bvh, bvl);
      }
      __syncthreads();
      for (int ch = 0; ch < 8; ++ch) {
        uint4 avh[4], avl[4], bvh[2], bvl[2];
        if (ch < 7) {
          load_pair<4>(AsrcH, AsrcL, m0A, (ch + 1) * 64, avh, avl);
          load_pair<2>(WsrcH, WsrcL, wrow0A, (ch + 1) * 64, bvh, bvl);
        }
        mfma3<4,2,2>(As, Bs, wmA, wnA, am, ac);
        __syncthreads();
        if (ch < 7) {
          write_pair<4,128>(As, avh, avl);
          write_pair<2,64>(Bs, bvh, bvl);
          __syncthreads();
        }
      }
      if (typeA == 0) {
        stage_x<128>(x, m0A, i, As);
        __syncthreads();
        mfma_fold<4,2>(As, WX, wmA, wnA, 0, 32, am, ac);
      }
      // epilogue
      if (typeA == 0) {
        const bool isR = (col0A < 512);
#pragma unroll
        for (int fm = 0; fm < 4; ++fm)
#pragma unroll
        for (int fn = 0; fn < 2; ++fn)
#pragma unroll
        for (int r = 0; r < 4; ++r) {
          int m = m0A + wmA + fm * 16 + lh * 4 + r;
          int n = col0A + wnA + fn * 16 + lr;
          float v = am[fm][fn][r] + ac[fm][fn][r] * INV_SC + b0[n];
          float s = sigm(v);
          if (isR) {
            float rh = s * H0[(size_t)m * 512 + n];
            split2(rh, RH0H[(size_t)m * 512 + n], RH0L[(size_t)m * 512 + n]);
          } else {
            Z0[(size_t)m * 512 + (n - 512)] = s;
          }
        }
      } else if (typeA == 1) {
#pragma unroll
        for (int fm = 0; fm < 4; ++fm)
#pragma unroll
        for (int fn = 0; fn < 2; ++fn)
#pragma unroll
        for (int r = 0; r < 4; ++r) {
          int m = m0A + wmA + fm * 16 + lh * 4 + r;
          int c1 = col0A - 1024 + wnA + fn * 16 + lr;
          GI1[(size_t)m * 1536 + c1] = am[fm][fn][r] + ac[fm][fn][r] * INV_SC + b1[c1];
        }
      } else {
#pragma unroll
        for (int fm = 0; fm < 4; ++fm)
#pragma unroll
        for (int fn = 0; fn < 2; ++fn)
#pragma unroll
        for (int r = 0; r < 4; ++r) {
          int m = m0A + wmA + fm * 16 + lh * 4 + r;
          int c = col0A - 2560 + wnA + fn * 16 + lr;
          RZ1[(size_t)m * 1024 + c] = am[fm][fn][r] + ac[fm][fn][r] * INV_SC;
        }
      }
    }
    ++lg; gbar(bar, bid, lg);

    // ========================= PHASE B =========================
    bool activeB = isN0 ? (i < SEQ) : (i >= 1);
    if (activeB) {
      f32x4 am[2][1] = {}, ac[2][1] = {};
      if (isN0) {
        {
          uint4 avh[2], avl[2], bvh[1], bvl[1];
          load_pair<2>(RH0H, RH0L, m0B, 0, avh, avl);
          load_pair<1>(WH0Hp, WH0Lp, 1024 + col0B, 0, bvh, bvl);
          write_pair<2,128>(As, avh, avl);
          write_pair<1,64>(Bs, bvh, bvl);
        }
        __syncthreads();
        for (int ch = 0; ch < 8; ++ch) {
          uint4 avh[2], avl[2], bvh[1], bvl[1];
          if (ch < 7) {
            load_pair<2>(RH0H, RH0L, m0B, (ch + 1) * 64, avh, avl);
            load_pair<1>(WH0Hp, WH0Lp, 1024 + col0B, (ch + 1) * 64, bvh, bvl);
          }
          mfma3<2,1,2>(As, Bs, wmB, wnB, am, ac);
          __syncthreads();
          if (ch < 7) {
            write_pair<2,128>(As, avh, avl);
            write_pair<1,64>(Bs, bvh, bvl);
            __syncthreads();
          }
        }
        stage_x<64>(x, m0B, i, As);
        __syncthreads();
        mfma_fold<2,1>(As, WX, wmB, wnB, 64, 80, am, ac);
#pragma unroll
        for (int fm = 0; fm < 2; ++fm)
#pragma unroll
        for (int r = 0; r < 4; ++r) {
          int m = m0B + wmB + fm * 16 + lh * 4 + r;
          int n = col0B + wnB + lr;
          float nn = tanh_f(am[fm][0][r] + ac[fm][0][r] * INV_SC + b0[1024 + n]);
          float z = Z0[(size_t)m * 512 + n];
          float hnew = (1.f - z) * nn + z * H0[(size_t)m * 512 + n];
          H0[(size_t)m * 512 + n] = hnew;
          split2(hnew, H0HI[(size_t)m * 512 + n], H0LO[(size_t)m * 512 + n]);
        }
      } else {
        {
          float4 gv[4], rv[4], hv[4]; uint4 bvh[1], bvl[1];
          load_rh1(GI1, RZ1, H1R, m0B, 0, gv, rv, hv);
          load_pair<1>(WH1Hp, WH1Lp, 1024 + col0B, 0, bvh, bvl);
          write_rh1(As, gv, rv, hv);
          write_pair<1,64>(Bs, bvh, bvl);
        }
        __syncthreads();
        for (int ch = 0; ch < 8; ++ch) {
          float4 gv[4], rv[4], hv[4]; uint4 bvh[1], bvl[1];
          if (ch < 7) {
            load_rh1(GI1, RZ1, H1R, m0B, ch + 1, gv, rv, hv);
            load_pair<1>(WH1Hp, WH1Lp, 1024 + col0B, (ch + 1) * 64, bvh, bvl);
          }
          mfma3<2,1,2>(As, Bs, wmB, wnB, am, ac);
          __syncthreads();
          if (ch < 7) {
            write_rh1(As, gv, rv, hv);
            write_pair<1,64>(Bs, bvh, bvl);
            __syncthreads();
          }
        }
#pragma unroll
        for (int fm = 0; fm < 2; ++fm)
#pragma unroll
        for (int r = 0; r < 4; ++r) {
          int m = m0B + wmB + fm * 16 + lh * 4 + r;
          int n = col0B + wnB + lr;
          float z = sigm(GI1[(size_t)m * 1536 + 512 + n] + RZ1[(size_t)m * 1024 + 512 + n]);
          float nn = tanh_f(GI1[(size_t)m * 1536 + 1024 + n] + am[fm][0][r] + ac[fm][0][r] * INV_SC);
          float hnew = (1.f - z) * nn + z * H1R[(size_t)m * 512 + n];
          H1W[(size_t)m * 512 + n] = hnew;
          split2(hnew, H1HIw[(size_t)m * 512 + n], H1LOw[(size_t)m * 512 + n]);
        }
      }
    }
    ++lg; gbar(bar, bid, lg);
  }

  // ========================= PROJECTION (single f16) =========================
  {
    const f16* H1F = (const f16*)(ws + OFF_H1HIA);  // final write at i=512 -> buf A
    const int mgP = bid >> 6, slotP = bid & 63;
    const int m0 = mgP * 128, col0 = slotP * 48;
    const int wm = wid * 32;
    f32x4 acc[2][3] = {};
    {
      uint4 av[4], bv[2];
      load_ldm<4,1024>(H1F, m0, 0, av);
      load_ldm<2,384>(WPHp, col0, 0, bv);
      write_ch<4,1024>(As, av); write_ch<2,384>(Bs, bv);
    }
    __syncthreads();
    for (int ch = 0; ch < 8; ++ch) {
      uint4 av[4], bv[2];
      if (ch < 7) { load_ldm<4,1024>(H1F, m0, (ch + 1) * 64, av); load_ldm<2,384>(WPHp, col0, (ch + 1) * 64, bv); }
      mfma_tile<2,3,2>(As, Bs, wm, 0, acc);
      __syncthreads();
      if (ch < 7) { write_ch<4,1024>(As, av); write_ch<2,384>(Bs, bv); __syncthreads(); }
    }
#pragma unroll
    for (int fm = 0; fm < 2; ++fm)
#pragma unroll
    for (int fn = 0; fn < 3; ++fn)
#pragma unroll
    for (int r = 0; r < 4; ++r) {
      int m = m0 + wm + fm * 16 + lh * 4 + r;
      int n = col0 + fn * 16 + lr;
      out[(size_t)m * 3072 + n] = acc[fm][fn][r] + bp[n];
    }
  }
}

// ---------------------------------------------------------------------------
extern "C" void kernel_launch(void* const* d_in, const int* in_sizes, int n_in,
                              void* d_out, int out_size, void* d_ws, size_t ws_size,
                              hipStream_t stream) {
  (void)in_sizes; (void)n_in; (void)out_size; (void)ws_size; // needs ws >= ~27MB
  const float* x   = (const float*)d_in[0];
  const float* Wi0 = (const float*)d_in[1];
  const float* Wh0 = (const float*)d_in[2];
  const float* b0  = (const float*)d_in[3];
  const float* Wi1 = (const float*)d_in[4];
  const float* Wh1 = (const float*)d_in[5];
  const float* b1  = (const float*)d_in[6];
  const float* Wp  = (const float*)d_in[7];
  const float* bp  = (const float*)d_in[8];
  char* ws = (char*)d_ws;
  hipLaunchKernelGGL(gru_setup, dim3(512), dim3(NT), 0, stream, Wi0, Wh0, Wi1, Wh1, Wp, ws);
  hipLaunchKernelGGL(gru_main, dim3(NBLK), dim3(NT), 0, stream,
                     x, b0, b1, bp, (float*)d_out, ws);
}